// Round 2
// baseline (189.432 us; speedup 1.0000x reference)
//
#include <hip/hip_runtime.h>

// Trilinear feature-grid interpolation.
// grid layout: [R][R][R][3] = [z][y][x][c], R=256, fp32.
// input: [N][3] = (x, y, z) per point in [0,1).
//
// Each point gathers 4 row-segments of 6 contiguous floats (two x-adjacent
// corners x 3 channels). Segment float-base indices all share parity
// (deltas 768 and 196608 are even), so we align down to an even index and
// issue 2x 16B loads per segment -> 8 dwordx4 gathers per point, all
// independent, drained by a single waitcnt.

typedef float f4 __attribute__((ext_vector_type(4)));
typedef f4 f4a8 __attribute__((aligned(8)));   // 16B load, 8B-aligned (HW needs only 4B align)

__global__ __launch_bounds__(256) void fgrid3d_kernel(
        const float* __restrict__ inp,
        const float* __restrict__ grid,
        float* __restrict__ out,
        int n) {
    int i = blockIdx.x * blockDim.x + threadIdx.x;
    if (i >= n) return;

    float px = inp[3 * i + 0];
    float py = inp[3 * i + 1];
    float pz = inp[3 * i + 2];

    float sx = px * 255.0f;
    float sy = py * 255.0f;
    float sz = pz * 255.0f;

    int xl = (int)floorf(sx); xl = xl < 0 ? 0 : (xl > 254 ? 254 : xl);
    int yl = (int)floorf(sy); yl = yl < 0 ? 0 : (yl > 254 ? 254 : yl);
    int zl = (int)floorf(sz); zl = zl < 0 ? 0 : (zl > 254 ? 254 : zl);

    float tx = sx - (float)xl;
    float ty = sy - (float)yl;
    float tz = sz - (float)zl;

    // float index of segment (zl,yl); other three at +768, +196608, +197376
    int b00 = (zl * 65536 + yl * 256 + xl) * 3;
    int a00 = b00 & ~1;          // even-aligned (8B) float index
    bool d  = (b00 & 1) != 0;    // uniform selector for all 4 segments

    const float* g00 = grid + a00;            // (zl,yl)
    const float* g10 = g00 + 196608;          // (zu,yl)

    // 8 independent 16B gathers, all in flight together.
    f4 A0 = *(const f4a8*)(g00);
    f4 A1 = *(const f4a8*)(g00 + 4);
    f4 B0 = *(const f4a8*)(g00 + 768);        // (zl,yu)
    f4 B1 = *(const f4a8*)(g00 + 772);
    f4 C0 = *(const f4a8*)(g10);
    f4 C1 = *(const f4a8*)(g10 + 4);
    f4 D0 = *(const f4a8*)(g10 + 768);        // (zu,yu)
    f4 D1 = *(const f4a8*)(g10 + 772);

    // Extract the 6 segment floats with static-index selects (rule #20: no
    // runtime vector indexing -> no scratch).
#define EXTRACT6(lo, hi, s)            \
    do {                               \
        s[0] = d ? lo.y : lo.x;        \
        s[1] = d ? lo.z : lo.y;        \
        s[2] = d ? lo.w : lo.z;        \
        s[3] = d ? hi.x : lo.w;        \
        s[4] = d ? hi.y : hi.x;        \
        s[5] = d ? hi.z : hi.y;        \
    } while (0)

    float s00[6], s01[6], s10[6], s11[6];
    EXTRACT6(A0, A1, s00);
    EXTRACT6(B0, B1, s01);
    EXTRACT6(C0, C1, s10);
    EXTRACT6(D0, D1, s11);
#undef EXTRACT6

    float o[3];
#pragma unroll
    for (int c = 0; c < 3; ++c) {
        float c00 = s00[c] * (1.0f - tx) + s00[c + 3] * tx;
        float c01 = s01[c] * (1.0f - tx) + s01[c + 3] * tx;
        float c10 = s10[c] * (1.0f - tx) + s10[c + 3] * tx;
        float c11 = s11[c] * (1.0f - tx) + s11[c + 3] * tx;
        float c0 = c00 * (1.0f - ty) + c01 * ty;
        float c1 = c10 * (1.0f - ty) + c11 * ty;
        o[c] = c0 * (1.0f - tz) + c1 * tz;
    }

    out[3 * i + 0] = o[0];
    out[3 * i + 1] = o[1];
    out[3 * i + 2] = o[2];
}

extern "C" void kernel_launch(void* const* d_in, const int* in_sizes, int n_in,
                              void* d_out, int out_size, void* d_ws, size_t ws_size,
                              hipStream_t stream) {
    const float* inp  = (const float*)d_in[0];  // [N][3]
    const float* grid = (const float*)d_in[1];  // [256][256][256][3]
    float* out = (float*)d_out;                 // [N][3]

    int n = in_sizes[0] / 3;
    int threads = 256;
    int blocks = (n + threads - 1) / threads;
    fgrid3d_kernel<<<blocks, threads, 0, stream>>>(inp, grid, out, n);
}